// Round 1
// baseline (305.274 us; speedup 1.0000x reference)
//
#include <hip/hip_runtime.h>
#include <hip/hip_bf16.h>

typedef __attribute__((ext_vector_type(8))) short short8;
typedef __attribute__((ext_vector_type(4))) short short4v;
typedef __attribute__((ext_vector_type(4))) float f32x4;

#define DEVI static __device__ __forceinline__

constexpr int T_SEQ = 256, DK = 128, DV = 128, CH = 64, NCH = 4;
constexpr int NPAIR = 16 * 32;
constexpr size_t OUT_ELEMS = (size_t)NPAIR * T_SEQ * DV;

// ---- LDS layout (bytes) ----
constexpr int OFF_SB   = 0;       // S_b [dv=128][dk=128] bf16 stride 256 (S transposed)
constexpr int OFF_KC   = 32768;   // kc  [j=64][d=128]  bf16 stride 256
constexpr int OFF_KCT  = 49152;   // kcT [d=128][j=64]  bf16 stride 128
constexpr int OFF_KRQS = 65536;   // kr then qs [i=64][d=128] bf16 stride 256
constexpr int OFF_V    = 81920;   // vbT -> Rt -> vnT [dv=128][j=64] bf16 stride 128
constexpr int OFF_B    = 98304;   // B / B2 / Mc [64][64] bf16 stride 128
constexpr int OFF_BT   = 106496;  // BT, then N_buf [64][64]
constexpr int OFF_NT   = 114688;  // NT [64][64]
constexpr int OFF_GC   = 122880;  // gc[256] f32
constexpr int OFF_BETA = 123904;  // beta[256] f32
constexpr int OFF_EPOS = 124928;  // epos[64] f32
constexpr int OFF_ENEG = 125184;  // eneg[64] f32
constexpr int OFF_WS   = 125440;  // wave scan sums[8]
constexpr int LDS_BYTES = 125472;
// out staging reuses OFF_KC..OFF_KC+32KB (f32 [64][128]); final S staging uses 0..64KB.

DEVI unsigned short f2bf(float f) {
  union { float f; unsigned u; } a; a.f = f;
  unsigned r = a.u + 0x7fffu + ((a.u >> 16) & 1u);   // round-nearest-even
  return (unsigned short)(r >> 16);
}
DEVI float bf2f(unsigned short h) {
  union { unsigned u; float f; } a; a.u = ((unsigned)h) << 16;
  return a.f;
}

DEVI f32x4 mfma(short8 a, short8 b, f32x4 c) {
  return __builtin_amdgcn_mfma_f32_16x16x32_bf16(a, b, c, 0, 0, 0);
}

// swizzled fragment load: 16B of bf16 at (row, k0..k0+7); k0 multiple of 8
DEVI short8 ldf(const char* s, int stride, int row, int k0) {
  return *(const short8*)(s + row * stride + ((((row & 7) << 4)) ^ (k0 * 2)));
}
// swizzled 4x bf16 store (col0 multiple of 4)
DEVI void st4(char* s, int stride, int row, int col0, f32x4 v) {
  short4v p;
  p[0] = (short)f2bf(v[0]); p[1] = (short)f2bf(v[1]);
  p[2] = (short)f2bf(v[2]); p[3] = (short)f2bf(v[3]);
  *(short4v*)(s + row * stride + (((row & 7) << 4) ^ (col0 * 2))) = p;
}
// swizzled single bf16 store
DEVI void st1(char* s, int stride, int row, int col, float f) {
  *(unsigned short*)(s + row * stride + (((row & 7) << 4) ^ (col * 2))) = f2bf(f);
}

__global__ __launch_bounds__(512, 1)
void cra_fwd(const float* __restrict__ qg_, const float* __restrict__ kg_,
             const float* __restrict__ vg_, const float* __restrict__ gg_,
             const float* __restrict__ bg_, const float* __restrict__ s0g_,
             float* __restrict__ outg_)
{
  extern __shared__ char sm[];
  const int tid = threadIdx.x;
  const int lane = tid & 63, w = tid >> 6;
  const int l15 = lane & 15, l4 = lane >> 4;
  const int pair = blockIdx.x;

  const size_t rowbase = (size_t)pair * T_SEQ;
  const float* qg = qg_ + rowbase * DK;
  const float* kg = kg_ + rowbase * DK;
  const float* vg = vg_ + rowbase * DV;
  float* outg = outg_ + rowbase * DV;
  float* soutg = outg_ + OUT_ELEMS + (size_t)pair * DK * DV;

  float* gc    = (float*)(sm + OFF_GC);
  float* bet   = (float*)(sm + OFF_BETA);
  float* eposA = (float*)(sm + OFF_EPOS);
  float* enegA = (float*)(sm + OFF_ENEG);
  float* wsum  = (float*)(sm + OFF_WS);

  // ---- init state regs S[dk][dv]: wave w owns dk-block w*16; C-layout m=dk, n=dv
  f32x4 Sacc[8];
  {
    const float* Sp = s0g_ + (size_t)pair * DK * DV;
    const int dk0 = w * 16 + l4 * 4;
#pragma unroll
    for (int tn = 0; tn < 8; ++tn) {
      const int dv = tn * 16 + l15;
#pragma unroll
      for (int rr = 0; rr < 4; ++rr)
        Sacc[tn][rr] = Sp[(size_t)(dk0 + rr) * DV + dv];
    }
  }

  // ---- cumsum of g; stage beta
  if (tid < 256) {
    float x = gg_[rowbase + tid];
    bet[tid] = bg_[rowbase + tid];
#pragma unroll
    for (int d = 1; d < 64; d <<= 1) {
      float y = __shfl_up(x, d, 64);
      if (lane >= d) x += y;
    }
    if (lane == 63) wsum[w] = x;
    gc[tid] = x;
  }
  __syncthreads();
  if (tid < 256) {
    float pre = 0.f;
    for (int j = 0; j < w; ++j) pre += wsum[j];
    gc[tid] += pre;
  }
  __syncthreads();

  const int r = tid >> 3, u = tid & 7;    // staging: row 0..63, 8 threads/row
  const f32x4 zero = {0.f, 0.f, 0.f, 0.f};
  const int tmB = (w >> 1) * 16;          // row-tile base for 64-row outputs

#pragma unroll 1
  for (int c = 0; c < NCH; ++c) {
    const int t0 = c * CH;
    // per-chunk scales
    if (tid < 64) {
      const float base = (c == 0) ? 0.f : gc[t0 - 1];
      const float lc = gc[t0 + tid] - base;
      eposA[tid] = __expf(lc);
      enegA[tid] = __expf(-lc);
    }
    // issue k/v global loads (latency overlap with scale compute)
    const float4* kp = (const float4*)(kg + (size_t)(t0 + r) * DK);
    const float4* vp = (const float4*)(vg + (size_t)(t0 + r) * DV);
    float4 kv[4], vv[4];
#pragma unroll
    for (int j = 0; j < 4; ++j) { kv[j] = kp[u + 8 * j]; vv[j] = vp[u + 8 * j]; }
    __syncthreads();   // scales ready; previous-chunk LDS reads all complete

    // ---- stage kr = beta*e^{lc}*k, kc = e^{-lc}*k, kcT, vbT = beta*v (transposed); dump S->S_b
    {
      const float be = bet[t0 + r], ep = eposA[r], en = enegA[r];
      const float krs = be * ep;
#pragma unroll
      for (int j = 0; j < 4; ++j) {
        const int col0 = 4 * (u + 8 * j);
        const float kf[4] = {kv[j].x, kv[j].y, kv[j].z, kv[j].w};
        const float vf[4] = {vv[j].x, vv[j].y, vv[j].z, vv[j].w};
        short4v pr, pc;
#pragma unroll
        for (int e = 0; e < 4; ++e) {
          pr[e] = (short)f2bf(kf[e] * krs);
          pc[e] = (short)f2bf(kf[e] * en);
        }
        *(short4v*)(sm + OFF_KRQS + r * 256 + (((r & 7) << 4) ^ (col0 * 2))) = pr;
        *(short4v*)(sm + OFF_KC   + r * 256 + (((r & 7) << 4) ^ (col0 * 2))) = pc;
#pragma unroll
        for (int e = 0; e < 4; ++e) {
          const int d = col0 + e;
          *(unsigned short*)(sm + OFF_KCT + d * 128 + (((d & 7) << 4) ^ (r * 2))) = f2bf(kf[e] * en);
          *(unsigned short*)(sm + OFF_V   + d * 128 + (((d & 7) << 4) ^ (r * 2))) = f2bf(vf[e] * be);
        }
      }
      // dump S regs -> S_b[dv][dk] (contiguous direction for C-layout)
      const int dk0 = w * 16 + l4 * 4;
#pragma unroll
      for (int tn = 0; tn < 8; ++tn)
        st4(sm + OFF_SB, 256, tn * 16 + l15, dk0, Sacc[tn]);
    }
    __syncthreads();

    // ---- KKT: A = strict_tril(kr @ kc^T); build B=-A, BT, N=I-A (regs + NT)
    f32x4 nreg[2];
#pragma unroll
    for (int s = 0; s < 2; ++s) {
      const int tn = (w & 1) * 2 + s;
      f32x4 acc = zero;
#pragma unroll
      for (int ks = 0; ks < 4; ++ks) {
        short8 af = ldf(sm + OFF_KRQS, 256, tmB + l15,   ks * 32 + l4 * 8);
        short8 bf = ldf(sm + OFF_KC,   256, tn * 16 + l15, ks * 32 + l4 * 8);
        acc = mfma(af, bf, acc);
      }
      const int i0 = tmB + l4 * 4, jj = tn * 16 + l15;
      f32x4 nr;
#pragma unroll
      for (int rr = 0; rr < 4; ++rr) {
        const int i = i0 + rr;
        const float Bv = (i > jj) ? -acc[rr] : 0.f;
        st1(sm + OFF_B,  128, i, jj, Bv);
        st1(sm + OFF_BT, 128, jj, i, Bv);
        nr[rr] = ((i == jj) ? 1.f : 0.f) + Bv;
      }
      nreg[s] = nr;
      st4(sm + OFF_NT, 128, jj, i0, nr);
    }

    // ---- R = vbT - (kr @ S)  (in place over OFF_V, transposed as Rt[dv][i])
#pragma unroll
    for (int s = 0; s < 4; ++s) {
      const int tn = (w & 1) * 4 + s;
      f32x4 acc = zero;
#pragma unroll
      for (int ks = 0; ks < 4; ++ks) {
        short8 af = ldf(sm + OFF_KRQS, 256, tmB + l15,   ks * 32 + l4 * 8);
        short8 bf = ldf(sm + OFF_SB,   256, tn * 16 + l15, ks * 32 + l4 * 8);
        acc = mfma(af, bf, acc);
      }
      const int dv = tn * 16 + l15, i0 = tmB + l4 * 4;
      char* p = sm + OFF_V + dv * 128 + (((dv & 7) << 4) ^ (i0 * 2));
      short4v old = *(const short4v*)p;
      short4v nw;
#pragma unroll
      for (int rr = 0; rr < 4; ++rr)
        nw[rr] = (short)f2bf(bf2f((unsigned short)old[rr]) - acc[rr]);
      *(short4v*)p = nw;
    }
    // issue q loads early (consumed after Neumann)
    const float4* qp = (const float4*)(qg + (size_t)(t0 + r) * DK);
    float4 qv[4];
#pragma unroll
    for (int j = 0; j < 4; ++j) qv[j] = qp[u + 8 * j];
    __syncthreads();

    // ---- Neumann doubling: N = (I+B^16...)(I+B)(...), B=-A, 5 iters exact for 64x64
#pragma unroll
    for (int it = 0; it < 5; ++it) {
      f32x4 b2[2];
#pragma unroll
      for (int s = 0; s < 2; ++s) {
        const int tn = (w & 1) * 2 + s;
        f32x4 acc = zero;
#pragma unroll
        for (int ks = 0; ks < 2; ++ks) {
          short8 af = ldf(sm + OFF_B,  128, tmB + l15,   ks * 32 + l4 * 8);
          short8 bf = ldf(sm + OFF_BT, 128, tn * 16 + l15, ks * 32 + l4 * 8);
          acc = mfma(af, bf, acc);
        }
        b2[s] = acc;
      }
      __syncthreads();
#pragma unroll
      for (int s = 0; s < 2; ++s) {
        const int tn = (w & 1) * 2 + s;
        const int i0 = tmB + l4 * 4, jj = tn * 16 + l15;
#pragma unroll
        for (int rr = 0; rr < 4; ++rr) st1(sm + OFF_B, 128, i0 + rr, jj, b2[s][rr]);
        if (it < 4) st4(sm + OFF_BT, 128, jj, i0, b2[s]);
      }
      __syncthreads();
#pragma unroll
      for (int s = 0; s < 2; ++s) {
        const int tn = (w & 1) * 2 + s;
#pragma unroll
        for (int ks = 0; ks < 2; ++ks) {
          short8 af = ldf(sm + OFF_B,  128, tmB + l15,   ks * 32 + l4 * 8);  // B2
          short8 bf = ldf(sm + OFF_NT, 128, tn * 16 + l15, ks * 32 + l4 * 8);
          nreg[s] = mfma(af, bf, nreg[s]);
        }
      }
      __syncthreads();
#pragma unroll
      for (int s = 0; s < 2; ++s) {
        const int tn = (w & 1) * 2 + s;
        const int i0 = tmB + l4 * 4, jj = tn * 16 + l15;
        st4(sm + OFF_NT, 128, jj, i0, nreg[s]);
        if (it == 4) {  // write N_buf [i][j] into OFF_BT (BT dead now)
#pragma unroll
          for (int rr = 0; rr < 4; ++rr) st1(sm + OFF_BT, 128, i0 + rr, jj, nreg[s][rr]);
        }
      }
      __syncthreads();
    }

    // ---- v_new = N @ R
    f32x4 vn[4];
#pragma unroll
    for (int s = 0; s < 4; ++s) {
      const int tn = (w & 1) * 4 + s;
      f32x4 acc = zero;
#pragma unroll
      for (int ks = 0; ks < 2; ++ks) {
        short8 af = ldf(sm + OFF_BT, 128, tmB + l15,   ks * 32 + l4 * 8);  // N_buf
        short8 bf = ldf(sm + OFF_V,  128, tn * 16 + l15, ks * 32 + l4 * 8);  // Rt
        acc = mfma(af, bf, acc);
      }
      vn[s] = acc;
    }
    __syncthreads();
    // write vnT (over Rt) and stage qs = e^{lc}*q (over kr)
#pragma unroll
    for (int s = 0; s < 4; ++s) {
      const int tn = (w & 1) * 4 + s;
      st4(sm + OFF_V, 128, tn * 16 + l15, tmB + l4 * 4, vn[s]);
    }
    {
      const float ep = eposA[r];
#pragma unroll
      for (int j = 0; j < 4; ++j) {
        const int col0 = 4 * (u + 8 * j);
        const float qf[4] = {qv[j].x, qv[j].y, qv[j].z, qv[j].w};
        short4v pq;
#pragma unroll
        for (int e = 0; e < 4; ++e) pq[e] = (short)f2bf(qf[e] * ep);
        *(short4v*)(sm + OFF_KRQS + r * 256 + (((r & 7) << 4) ^ (col0 * 2))) = pq;
      }
    }
    __syncthreads();

    // ---- out = qs @ S_b  (+ later intra)
    f32x4 outA[4];
#pragma unroll
    for (int s = 0; s < 4; ++s) {
      const int tn = (w & 1) * 4 + s;
      f32x4 acc = zero;
#pragma unroll
      for (int ks = 0; ks < 4; ++ks) {
        short8 af = ldf(sm + OFF_KRQS, 256, tmB + l15,   ks * 32 + l4 * 8);
        short8 bf = ldf(sm + OFF_SB,   256, tn * 16 + l15, ks * 32 + l4 * 8);
        acc = mfma(af, bf, acc);
      }
      outA[s] = acc;
    }
    // Mc = tril(qs @ kc^T, incl diag) -> OFF_B
#pragma unroll
    for (int s = 0; s < 2; ++s) {
      const int tn = (w & 1) * 2 + s;
      f32x4 acc = zero;
#pragma unroll
      for (int ks = 0; ks < 4; ++ks) {
        short8 af = ldf(sm + OFF_KRQS, 256, tmB + l15,   ks * 32 + l4 * 8);
        short8 bf = ldf(sm + OFF_KC,   256, tn * 16 + l15, ks * 32 + l4 * 8);
        acc = mfma(af, bf, acc);
      }
      const int i0 = tmB + l4 * 4, jj = tn * 16 + l15;
#pragma unroll
      for (int rr = 0; rr < 4; ++rr)
        st1(sm + OFF_B, 128, i0 + rr, jj, (jj <= i0 + rr) ? acc[rr] : 0.f);
    }
    __syncthreads();
    // out += Mc @ v_new
#pragma unroll
    for (int s = 0; s < 4; ++s) {
      const int tn = (w & 1) * 4 + s;
#pragma unroll
      for (int ks = 0; ks < 2; ++ks) {
        short8 af = ldf(sm + OFF_B, 128, tmB + l15,   ks * 32 + l4 * 8);
        short8 bf = ldf(sm + OFF_V, 128, tn * 16 + l15, ks * 32 + l4 * 8);
        outA[s] = mfma(af, bf, outA[s]);
      }
    }
    // ---- state: S = e^{G} * (S + kc^T @ v_new)
    {
      const float eG = eposA[CH - 1];
#pragma unroll
      for (int tn = 0; tn < 8; ++tn) {
#pragma unroll
        for (int ks = 0; ks < 2; ++ks) {
          short8 af = ldf(sm + OFF_KCT, 128, w * 16 + l15,  ks * 32 + l4 * 8);
          short8 bf = ldf(sm + OFF_V,   128, tn * 16 + l15, ks * 32 + l4 * 8);
          Sacc[tn] = mfma(af, bf, Sacc[tn]);
        }
#pragma unroll
        for (int rr = 0; rr < 4; ++rr) Sacc[tn][rr] *= eG;
      }
    }
    __syncthreads();
    // ---- write out chunk (stage fp32 in LDS over kc/kcT, then coalesced store)
    {
      float* OST = (float*)(sm + OFF_KC);
#pragma unroll
      for (int s = 0; s < 4; ++s) {
        const int tn = (w & 1) * 4 + s;
        const int i0 = tmB + l4 * 4, dv = tn * 16 + l15;
#pragma unroll
        for (int rr = 0; rr < 4; ++rr) OST[(i0 + rr) * 128 + dv] = outA[s][rr];
      }
    }
    __syncthreads();
    {
      float4* og = (float4*)(outg + (size_t)t0 * DV);
      const float4* os = (const float4*)(sm + OFF_KC);
#pragma unroll
      for (int j = 0; j < 4; ++j) og[tid + 512 * j] = os[tid + 512 * j];
    }
    __syncthreads();
  } // chunk loop

  // ---- final state: stage fp32 [dk][dv] at LDS 0..64KB, coalesced store
  {
    float* SST = (float*)sm;
    const int dk0 = w * 16 + l4 * 4;
#pragma unroll
    for (int tn = 0; tn < 8; ++tn) {
      const int dv = tn * 16 + l15;
#pragma unroll
      for (int rr = 0; rr < 4; ++rr) SST[(dk0 + rr) * 128 + dv] = Sacc[tn][rr];
    }
  }
  __syncthreads();
  {
    float4* sg = (float4*)soutg;
    const float4* ss = (const float4*)sm;
#pragma unroll
    for (int j = 0; j < 8; ++j) sg[tid + 512 * j] = ss[tid + 512 * j];
  }
}

extern "C" void kernel_launch(void* const* d_in, const int* in_sizes, int n_in,
                              void* d_out, int out_size, void* d_ws, size_t ws_size,
                              hipStream_t stream) {
  (void)in_sizes; (void)n_in; (void)out_size; (void)d_ws; (void)ws_size;
  const float* q  = (const float*)d_in[0];
  const float* k  = (const float*)d_in[1];
  const float* v  = (const float*)d_in[2];
  const float* g  = (const float*)d_in[3];
  const float* b  = (const float*)d_in[4];
  const float* s0 = (const float*)d_in[5];
  hipFuncSetAttribute((const void*)cra_fwd,
                      hipFuncAttributeMaxDynamicSharedMemorySize, LDS_BYTES);
  hipLaunchKernelGGL(cra_fwd, dim3(NPAIR), dim3(512), LDS_BYTES, stream,
                     q, k, v, g, b, s0, (float*)d_out);
}